// Round 1
// baseline (135.201 us; speedup 1.0000x reference)
//
#include <hip/hip_runtime.h>

#define HH 128
#define WW 128
#define NPX (HH * WW)
#define KK 10

// Per-gaussian packed params: PP[2g] = (a, 2b, c, mean_x); PP[2g+1] = (mean_y, r, g, b)
__device__ __forceinline__ void compute_params(
    const float* __restrict__ means, const float* __restrict__ rots,
    const float* __restrict__ lscales, const float* __restrict__ cols,
    int g, float4* p0, float4* p1) {
  float mx = means[2 * g], my = means[2 * g + 1];
  float th = rots[g];
  float s = __sinf(th), c = __cosf(th);
  float ivx = __expf(-2.0f * lscales[2 * g]);
  float ivy = __expf(-2.0f * lscales[2 * g + 1]);
  float a  = c * c * ivx + s * s * ivy;
  float cc = s * s * ivx + c * c * ivy;
  float b2 = 2.0f * (c * s * (ivx - ivy));
  *p0 = make_float4(a, b2, cc, mx);
  *p1 = make_float4(my, cols[3 * g], cols[3 * g + 1], cols[3 * g + 2]);
}

__global__ void params_kernel(const float* __restrict__ means,
                              const float* __restrict__ rots,
                              const float* __restrict__ lscales,
                              const float* __restrict__ cols,
                              int nG, float4* __restrict__ PP) {
  int g = blockIdx.x * blockDim.x + threadIdx.x;
  if (g >= nG) return;
  float4 p0, p1;
  compute_params(means, rots, lscales, cols, g, &p0, &p1);
  PP[2 * g]     = p0;
  PP[2 * g + 1] = p1;
}

// Sorted insertion of (v, vi) into descending vals[]/ids[]; strict > keeps
// lower-index-first tie-break (matches jax.lax.top_k since we insert in
// ascending global-index order).
__device__ __forceinline__ void bubble_insert(float vals[KK], int ids[KK],
                                              float v, int vi) {
#pragma unroll
  for (int k = 0; k < KK; ++k) {
    bool sw = v > vals[k];
    float tv = vals[k];
    int ti = ids[k];
    vals[k] = sw ? v : tv;
    ids[k]  = sw ? vi : ti;
    v  = sw ? tv : v;
    vi = sw ? ti : vi;
  }
}

// Kernel 1: per-(pixel, segment) top-10. Grid: (64 tiles, S segments), 256 thr.
__global__ __launch_bounds__(256) void topk_seg_kernel(
    const float4* __restrict__ PP, int nG, int S,
    float* __restrict__ alphaBuf, int* __restrict__ idxBuf) {
  int tile = blockIdx.x;
  int seg  = blockIdx.y;
  int t = threadIdx.x;
  int x = ((tile & 7) << 4) | (t & 15);
  int y = ((tile >> 3) << 4) | (t >> 4);
  int p = y * WW + x;
  float px = (float)x + 0.5f;
  float py = (float)y + 0.5f;

  int Gseg = nG / S;
  int g0 = seg * Gseg;

  __shared__ float4 lds[256];  // 128 gaussians per chunk

  float vals[KK];
  int ids[KK];
#pragma unroll
  for (int k = 0; k < KK; ++k) { vals[k] = -1.0f; ids[k] = 0; }

  for (int c0 = 0; c0 < Gseg; c0 += 128) {
    int nchunk = min(128, Gseg - c0);
    __syncthreads();
    if (t < 2 * nchunk) lds[t] = PP[2 * (g0 + c0) + t];
    __syncthreads();
    for (int gg = 0; gg < nchunk; ++gg) {
      float4 q0 = lds[2 * gg];
      float4 q1 = lds[2 * gg + 1];
      float dx = px - q0.w;
      float dy = py - q1.x;
      float q = fmaf(dx, fmaf(q0.y, dy, q0.x * dx), q0.z * dy * dy);
      float alpha = __expf(-0.5f * q);
      if (alpha > vals[KK - 1]) {
        bubble_insert(vals, ids, alpha, g0 + c0 + gg);
      }
    }
  }
#pragma unroll
  for (int k = 0; k < KK; ++k) {
    alphaBuf[(seg * KK + k) * NPX + p] = vals[k];
    idxBuf [(seg * KK + k) * NPX + p] = ids[k];
  }
}

// Kernel 2: merge S sorted top-10 lists -> global top-10, composite.
__global__ __launch_bounds__(256) void merge_kernel(
    const float* __restrict__ alphaBuf, const int* __restrict__ idxBuf,
    const float4* __restrict__ PP, int S, float* __restrict__ out) {
  int p = blockIdx.x * 256 + threadIdx.x;
  if (p >= NPX) return;
  float vals[KK];
  int ids[KK];
#pragma unroll
  for (int k = 0; k < KK; ++k) { vals[k] = -1.0f; ids[k] = 0; }

  for (int s = 0; s < S; ++s) {
    for (int k = 0; k < KK; ++k) {
      float a = alphaBuf[(s * KK + k) * NPX + p];
      if (a > vals[KK - 1]) {
        bubble_insert(vals, ids, a, idxBuf[(s * KK + k) * NPX + p]);
      } else {
        break;  // per-segment list is descending; rest can't displace
      }
    }
  }

  float trans = 1.0f;
  float r = 0.0f, g = 0.0f, b = 0.0f;
#pragma unroll
  for (int k = 0; k < KK; ++k) {
    float a = vals[k];
    float w = a * trans;
    float4 q1 = PP[2 * ids[k] + 1];
    r += w * q1.y;
    g += w * q1.z;
    b += w * q1.w;
    trans *= (1.0f - a);
  }
  out[3 * p + 0] = r;
  out[3 * p + 1] = g;
  out[3 * p + 2] = b;
}

// Fallback: monolithic, params computed on the fly in LDS (no workspace).
__global__ __launch_bounds__(256) void mono_kernel(
    const float* __restrict__ means, const float* __restrict__ rots,
    const float* __restrict__ lscales, const float* __restrict__ cols,
    int nG, float* __restrict__ out) {
  int tile = blockIdx.x;
  int t = threadIdx.x;
  int x = ((tile & 7) << 4) | (t & 15);
  int y = ((tile >> 3) << 4) | (t >> 4);
  int p = y * WW + x;
  float px = (float)x + 0.5f;
  float py = (float)y + 0.5f;

  __shared__ float4 lds[512];

  float vals[KK];
  int ids[KK];
#pragma unroll
  for (int k = 0; k < KK; ++k) { vals[k] = -1.0f; ids[k] = 0; }

  for (int c0 = 0; c0 < nG; c0 += 256) {
    int nchunk = min(256, nG - c0);
    __syncthreads();
    if (t < nchunk) {
      float4 p0, p1;
      compute_params(means, rots, lscales, cols, c0 + t, &p0, &p1);
      lds[2 * t]     = p0;
      lds[2 * t + 1] = p1;
    }
    __syncthreads();
    for (int gg = 0; gg < nchunk; ++gg) {
      float4 q0 = lds[2 * gg];
      float4 q1 = lds[2 * gg + 1];
      float dx = px - q0.w;
      float dy = py - q1.x;
      float q = fmaf(dx, fmaf(q0.y, dy, q0.x * dx), q0.z * dy * dy);
      float alpha = __expf(-0.5f * q);
      if (alpha > vals[KK - 1]) {
        bubble_insert(vals, ids, alpha, c0 + gg);
      }
    }
  }

  float trans = 1.0f;
  float r = 0.0f, g = 0.0f, b = 0.0f;
#pragma unroll
  for (int k = 0; k < KK; ++k) {
    float a = vals[k];
    float w = a * trans;
    int i = ids[k];
    r += w * cols[3 * i + 0];
    g += w * cols[3 * i + 1];
    b += w * cols[3 * i + 2];
    trans *= (1.0f - a);
  }
  out[3 * p + 0] = r;
  out[3 * p + 1] = g;
  out[3 * p + 2] = b;
}

extern "C" void kernel_launch(void* const* d_in, const int* in_sizes, int n_in,
                              void* d_out, int out_size, void* d_ws, size_t ws_size,
                              hipStream_t stream) {
  const float* means   = (const float*)d_in[0];
  const float* rots    = (const float*)d_in[1];
  const float* lscales = (const float*)d_in[2];
  const float* cols    = (const float*)d_in[3];
  float* out = (float*)d_out;
  int nG = in_sizes[1];  // rotations: one per gaussian

  // Workspace layout: [alphaBuf: S*K*NPX f32][idxBuf: S*K*NPX i32][PP: nG*2 float4]
  int S = 16;
  while (S > 1 &&
         ((size_t)2 * S * KK * NPX * 4 + (size_t)nG * 32 > ws_size || (nG % S) != 0)) {
    S >>= 1;
  }
  bool seg_ok = ((size_t)2 * S * KK * NPX * 4 + (size_t)nG * 32 <= ws_size) &&
                (nG % S == 0) && (nG / S >= KK);

  if (seg_ok) {
    float* alphaBuf = (float*)d_ws;
    int*   idxBuf   = (int*)((char*)d_ws + (size_t)S * KK * NPX * 4);
    float4* PP      = (float4*)((char*)d_ws + (size_t)2 * S * KK * NPX * 4);
    params_kernel<<<(nG + 255) / 256, 256, 0, stream>>>(means, rots, lscales, cols, nG, PP);
    topk_seg_kernel<<<dim3(NPX / 256, S), 256, 0, stream>>>(PP, nG, S, alphaBuf, idxBuf);
    merge_kernel<<<NPX / 256, 256, 0, stream>>>(alphaBuf, idxBuf, PP, S, out);
  } else {
    mono_kernel<<<NPX / 256, 256, 0, stream>>>(means, rots, lscales, cols, nG, out);
  }
}